// Round 2
// baseline (292.991 us; speedup 1.0000x reference)
//
#include <hip/hip_runtime.h>

typedef unsigned short u16;
typedef u16 u16x4 __attribute__((ext_vector_type(4)));
typedef float f32x4 __attribute__((ext_vector_type(4)));
typedef __bf16 bf16x8 __attribute__((ext_vector_type(8)));
typedef __bf16 bf16x4 __attribute__((ext_vector_type(4)));

#define M_DIM 8192   // B*H = 4*2048
#define N_DIM 1024   // O
#define K_DIM 4096   // I*(D+1) = 1024*4

__device__ __forceinline__ u16 f2bf(float f) {
  unsigned u = __float_as_uint(f);
  u += 0x7FFFu + ((u >> 16) & 1u);   // round-to-nearest-even
  return (u16)(u >> 16);
}

// ---- kernel 1: W2[o][i*4+d] = ws[o][i] * w[o][d], bf16 [N][K] ----
__global__ __launch_bounds__(256) void k_w2(const float* __restrict__ w,
                                            const float* __restrict__ ws,
                                            u16* __restrict__ w2) {
  int idx = blockIdx.x * 256 + threadIdx.x;  // idx = o*1024 + i
  int o = idx >> 10;
  float s = ws[idx];
  f32x4 wv = *(const f32x4*)(w + o * 4);
  u16x4 r;
  r[0] = f2bf(s * wv[0]); r[1] = f2bf(s * wv[1]);
  r[2] = f2bf(s * wv[2]); r[3] = f2bf(s * wv[3]);
  *(u16x4*)(w2 + (size_t)idx * 4) = r;
}

// ---- kernel 2: fused cvt+GEMM, double-buffered LDS, 1 barrier/K-step.
// Stage tile t+1 (A: global->reg->cvt->sA[nxt]; B: gll16->sB[nxt]) while
// computing tile t from sA/sB[cur]. The vmcnt wait for A regs lands AFTER
// the MFMA block, so HBM latency hides under compute instead of being
// exposed at the barrier. ----
typedef __attribute__((address_space(1))) const void gvoid_t;
typedef __attribute__((address_space(3))) void lvoid_t;
__device__ __forceinline__ void gll16(const void* g, void* l) {
  __builtin_amdgcn_global_load_lds((gvoid_t*)g, (lvoid_t*)l, 16, 0, 0);
}

__device__ __forceinline__ void cvt_store(u16* dst, f32x4 a) {
  bf16x4 b;
  b[0] = (__bf16)a[0]; b[1] = (__bf16)a[1];
  b[2] = (__bf16)a[2]; b[3] = (__bf16)a[3];
  *(bf16x4*)dst = b;   // ds_write_b64
}

__global__ __launch_bounds__(512) void k_gemm(const float* __restrict__ A,
                                              const u16* __restrict__ Bt,
                                              float* __restrict__ C) {
  __shared__ u16 sA[2][128 * 64];  // 2 x 16 KB bf16 (swizzled)
  __shared__ u16 sB[2][128 * 64];  // 2 x 16 KB bf16 (swizzled)

  const int t    = threadIdx.x;
  const int lane = t & 63;
  const int wid  = t >> 6;           // 0..7

  // XCD-locality swizzle: XCD x owns m-panels x*8..x*8+7; the 8 n-blocks
  // of each m-panel are co-resident on one L2 (A panel fetched once).
  const int L  = blockIdx.x;
  const int xc = L & 7;
  const int jj = L >> 3;             // 0..63
  const int m0 = (xc * 8 + (jj >> 3)) * 128;
  const int n0 = (jj & 7) * 128;

  // --- A staging geometry (fp32 -> bf16 in regs) ---
  // thread t handles rows (t>>4)+32j (j=0..3), fp32-quad q=t&15 of each.
  // LDS slot: 16B chunk c=q>>1 stored at c^(row&7); (32j)&7==0 so the
  // swizzled chunk index is the same for all 4 rows.
  const int ar  = t >> 4;            // base row 0..31
  const int aq  = t & 15;            // fp32 quad within 64-col k-step
  const int apc = (aq >> 1) ^ (ar & 7);
  const float* pA = A + (size_t)(m0 + ar) * K_DIM + aq * 4;
  const int lAoff = ar * 64 + apc * 8 + (aq & 1) * 4;

  // --- B staging via global_load_lds (swizzled) ---
  const int s0 = t, s1 = t + 512;
  const int r0 = s0 >> 3, c0 = (s0 & 7) ^ (r0 & 7);
  const int r1 = s1 >> 3, c1 = (s1 & 7) ^ (r1 & 7);
  const u16* gB0 = Bt + (size_t)(n0 + r0) * K_DIM + c0 * 8;
  const u16* gB1 = Bt + (size_t)(n0 + r1) * K_DIM + c1 * 8;
  const int lB0off = s0 * 8, lB1off = s1 * 8;

  // wave tile: 4(M)x2(N) waves of 32x64, each 2x4 MFMA 16x16x32 per k-step
  const int wm = (wid >> 1) * 32;
  const int wn = (wid & 1) * 64;
  const int fr = lane & 15;         // fragment row
  const int lc = lane >> 4;         // logical chunk within 32-wide k-step

  f32x4 acc[2][4];
#pragma unroll
  for (int i = 0; i < 2; i++)
#pragma unroll
    for (int j = 0; j < 4; j++) acc[i][j] = (f32x4){0.f, 0.f, 0.f, 0.f};

  // ---- prologue: stage tile 0 into buffer 0 ----
  f32x4 pf0 = *(const f32x4*)(pA);
  f32x4 pf1 = *(const f32x4*)(pA + (size_t)32 * K_DIM);
  f32x4 pf2 = *(const f32x4*)(pA + (size_t)64 * K_DIM);
  f32x4 pf3 = *(const f32x4*)(pA + (size_t)96 * K_DIM);
  gll16(gB0, sB[0] + lB0off); gll16(gB1, sB[0] + lB1off);
  gB0 += 64; gB1 += 64;
  cvt_store(sA[0] + lAoff,           pf0);
  cvt_store(sA[0] + lAoff + 32 * 64, pf1);
  cvt_store(sA[0] + lAoff + 64 * 64, pf2);
  cvt_store(sA[0] + lAoff + 96 * 64, pf3);
  __syncthreads();  // tile 0 ready (drains lgkm + vm)

  for (int k0 = 0; k0 < K_DIM; k0 += 64) {
    const int cur = (k0 >> 6) & 1;
    const int nxt = cur ^ 1;
    const bool has_next = (k0 + 64 < K_DIM);

    // issue tile t+1 loads: A regs first, then B gll16 (so the cvt_store
    // wait below is vmcnt(2), not a full drain).
    if (has_next) {
      pA += 64;
      pf0 = *(const f32x4*)(pA);
      pf1 = *(const f32x4*)(pA + (size_t)32 * K_DIM);
      pf2 = *(const f32x4*)(pA + (size_t)64 * K_DIM);
      pf3 = *(const f32x4*)(pA + (size_t)96 * K_DIM);
      gll16(gB0, sB[nxt] + lB0off); gll16(gB1, sB[nxt] + lB1off);
      gB0 += 64; gB1 += 64;
    }

    // ---- compute tile t from buffer cur ----
#pragma unroll
    for (int ks = 0; ks < 2; ks++) {
      bf16x8 af[2], bfr[4];
#pragma unroll
      for (int mi = 0; mi < 2; mi++) {
        int r  = wm + mi * 16 + fr;
        int pc = (ks * 4 + lc) ^ (r & 7);
        af[mi] = *(const bf16x8*)(sA[cur] + r * 64 + pc * 8);
      }
#pragma unroll
      for (int ni = 0; ni < 4; ni++) {
        int r  = wn + ni * 16 + fr;
        int pc = (ks * 4 + lc) ^ (r & 7);
        bfr[ni] = *(const bf16x8*)(sB[cur] + r * 64 + pc * 8);
      }
#pragma unroll
      for (int mi = 0; mi < 2; mi++)
#pragma unroll
        for (int ni = 0; ni < 4; ni++)
          acc[mi][ni] = __builtin_amdgcn_mfma_f32_16x16x32_bf16(
              af[mi], bfr[ni], acc[mi][ni], 0, 0, 0);
    }

    // ---- stage A(t+1) into the other buffer (wait lands here, after
    // compute) and close the iteration with ONE barrier ----
    if (has_next) {
      cvt_store(sA[nxt] + lAoff,           pf0);
      cvt_store(sA[nxt] + lAoff + 32 * 64, pf1);
      cvt_store(sA[nxt] + lAoff + 64 * 64, pf2);
      cvt_store(sA[nxt] + lAoff + 96 * 64, pf3);
      __syncthreads();  // next tile ready; also protects cur for reuse
    }
  }

  // C/D layout: col = lane&15, row = (lane>>4)*4 + reg
  const int cr = (lane >> 4) * 4;
  const int cc = lane & 15;
#pragma unroll
  for (int mi = 0; mi < 2; mi++)
#pragma unroll
    for (int ni = 0; ni < 4; ni++) {
      float* cp = C + (size_t)(m0 + wm + mi * 16 + cr) * N_DIM +
                  (n0 + wn + ni * 16 + cc);
#pragma unroll
      for (int r = 0; r < 4; r++) cp[(size_t)r * N_DIM] = acc[mi][ni][r];
    }
}

extern "C" void kernel_launch(void* const* d_in, const int* in_sizes, int n_in,
                              void* d_out, int out_size, void* d_ws, size_t ws_size,
                              hipStream_t stream) {
  const float* x  = (const float*)d_in[0];   // (4,2048,1024,4) fp32
  const float* w  = (const float*)d_in[1];   // (1024,4) fp32
  const float* ws = (const float*)d_in[2];   // (1024,1024) fp32
  float* out = (float*)d_out;                // (4,2048,1024) fp32 = C[M][N]

  u16* w2 = (u16*)d_ws;                      // 4.2M u16 = 8 MB

  k_w2<<<4096, 256, 0, stream>>>(w, ws, w2);
  k_gemm<<<512, 512, 0, stream>>>(x, w2, out);
}

// Round 3
// 290.718 us; speedup vs baseline: 1.0078x; 1.0078x over previous
//
#include <hip/hip_runtime.h>

typedef unsigned short u16;
typedef u16 u16x4 __attribute__((ext_vector_type(4)));
typedef u16 u16x8 __attribute__((ext_vector_type(8)));
typedef float f32x4 __attribute__((ext_vector_type(4)));
typedef __bf16 bf16x8 __attribute__((ext_vector_type(8)));
typedef __bf16 bf16x4 __attribute__((ext_vector_type(4)));

#define M_DIM 8192   // B*H = 4*2048
#define N_DIM 1024   // O
#define K_DIM 4096   // I*(D+1) = 1024*4

__device__ __forceinline__ u16 f2bf(float f) {
  unsigned u = __float_as_uint(f);
  u += 0x7FFFu + ((u >> 16) & 1u);   // round-to-nearest-even
  return (u16)(u >> 16);
}

// ---- kernel 1: W2[o][i*4+d] = ws[o][i] * w[o][d], bf16 [N][K] ----
__global__ __launch_bounds__(256) void k_w2(const float* __restrict__ w,
                                            const float* __restrict__ ws,
                                            u16* __restrict__ w2) {
  int idx = blockIdx.x * 256 + threadIdx.x;  // idx = o*1024 + i
  int o = idx >> 10;
  float s = ws[idx];
  f32x4 wv = *(const f32x4*)(w + o * 4);
  u16x4 r;
  r[0] = f2bf(s * wv[0]); r[1] = f2bf(s * wv[1]);
  r[2] = f2bf(s * wv[2]); r[3] = f2bf(s * wv[3]);
  *(u16x4*)(w2 + (size_t)idx * 4) = r;
}

// ---- kernel 2: fused cvt+GEMM, 2-deep reg pipeline + LDS double buffer.
// Half-step h: issue loads(tile h+2) -> compute(tile h) -> ds_write(tile
// h+1, loaded at h-1 => ~1.7 halves of latency cover) -> lgkmcnt(0) +
// raw s_barrier. No global_load_lds, so vmcnt is NEVER drained at the
// barrier: the compiler emits counted vmcnt for the reg uses and ~2 tiles
// of loads stay in flight per thread at all times. ----

__device__ __forceinline__ void cvt_store(u16* dst, f32x4 a) {
  bf16x4 b;
  b[0] = (__bf16)a[0]; b[1] = (__bf16)a[1];
  b[2] = (__bf16)a[2]; b[3] = (__bf16)a[3];
  *(bf16x4*)dst = b;   // ds_write_b64
}

__device__ __forceinline__ void lds_barrier() {
  asm volatile("s_waitcnt lgkmcnt(0)" ::: "memory");
  __builtin_amdgcn_s_barrier();
}

struct Set {
  f32x4 a0, a1, a2, a3;  // A fp32 quads (4 rows)
  u16x8 b0, b1;          // B bf16 16B chunks
};

__global__ __launch_bounds__(512, 4) void k_gemm(const float* __restrict__ A,
                                                 const u16* __restrict__ Bt,
                                                 float* __restrict__ C) {
  __shared__ u16 sA[2][128 * 64];  // 2 x 16 KB bf16 (swizzled)
  __shared__ u16 sB[2][128 * 64];  // 2 x 16 KB bf16 (swizzled)

  const int t    = threadIdx.x;
  const int lane = t & 63;
  const int wid  = t >> 6;           // 0..7

  // XCD-locality swizzle: XCD x owns m-panels x*8..x*8+7; the 8 n-blocks
  // of each m-panel are co-resident on one L2 (A panel fetched once).
  const int L  = blockIdx.x;
  const int xc = L & 7;
  const int jj = L >> 3;             // 0..63
  const int m0 = (xc * 8 + (jj >> 3)) * 128;
  const int n0 = (jj & 7) * 128;

  // --- A staging geometry (fp32 -> bf16 in regs) ---
  const int ar  = t >> 4;            // base row 0..31 (rows ar+32j)
  const int aq  = t & 15;            // fp32 quad within 64-col k-step
  const int apc = (aq >> 1) ^ (ar & 7);
  const float* pA = A + (size_t)(m0 + ar) * K_DIM + aq * 4;
  const int lAoff = ar * 64 + apc * 8 + (aq & 1) * 4;

  // --- B staging geometry (pre-swizzled global addr, linear LDS slot) ---
  const int s0 = t, s1 = t + 512;
  const int r0 = s0 >> 3, c0 = (s0 & 7) ^ (r0 & 7);
  const int r1 = s1 >> 3, c1 = (s1 & 7) ^ (r1 & 7);
  const u16* gB0 = Bt + (size_t)(n0 + r0) * K_DIM + c0 * 8;
  const u16* gB1 = Bt + (size_t)(n0 + r1) * K_DIM + c1 * 8;
  const int lB0off = s0 * 8, lB1off = s1 * 8;

  // wave tile: 4(M)x2(N) waves of 32x64, each 2x4 MFMA 16x16x32 per k-step
  const int wm = (wid >> 1) * 32;
  const int wn = (wid & 1) * 64;
  const int fr = lane & 15;         // fragment row
  const int lc = lane >> 4;         // logical chunk within 32-wide k-step

  f32x4 acc[2][4];
#pragma unroll
  for (int i = 0; i < 2; i++)
#pragma unroll
    for (int j = 0; j < 4; j++) acc[i][j] = (f32x4){0.f, 0.f, 0.f, 0.f};

#define LOAD_SET(S)                                   \
  do {                                                \
    S.a0 = *(const f32x4*)(pA);                       \
    S.a1 = *(const f32x4*)(pA + (size_t)32 * K_DIM);  \
    S.a2 = *(const f32x4*)(pA + (size_t)64 * K_DIM);  \
    S.a3 = *(const f32x4*)(pA + (size_t)96 * K_DIM);  \
    S.b0 = *(const u16x8*)(gB0);                      \
    S.b1 = *(const u16x8*)(gB1);                      \
    pA += 64; gB0 += 64; gB1 += 64;                   \
  } while (0)

#define WRITE_SET(S, bufA, bufB)                      \
  do {                                                \
    cvt_store((bufA) + lAoff,           S.a0);        \
    cvt_store((bufA) + lAoff + 32 * 64, S.a1);        \
    cvt_store((bufA) + lAoff + 64 * 64, S.a2);        \
    cvt_store((bufA) + lAoff + 96 * 64, S.a3);        \
    *(u16x8*)((bufB) + lB0off) = S.b0;                \
    *(u16x8*)((bufB) + lB1off) = S.b1;                \
  } while (0)

#define COMPUTE(bufA, bufB)                                          \
  do {                                                               \
    _Pragma("unroll")                                                \
    for (int ks = 0; ks < 2; ks++) {                                 \
      bf16x8 af[2], bfr[4];                                          \
      _Pragma("unroll")                                              \
      for (int mi = 0; mi < 2; mi++) {                               \
        int r  = wm + mi * 16 + fr;                                  \
        int pc = (ks * 4 + lc) ^ (r & 7);                            \
        af[mi] = *(const bf16x8*)((bufA) + r * 64 + pc * 8);         \
      }                                                              \
      _Pragma("unroll")                                              \
      for (int ni = 0; ni < 4; ni++) {                               \
        int r  = wn + ni * 16 + fr;                                  \
        int pc = (ks * 4 + lc) ^ (r & 7);                            \
        bfr[ni] = *(const bf16x8*)((bufB) + r * 64 + pc * 8);        \
      }                                                              \
      _Pragma("unroll")                                              \
      for (int mi = 0; mi < 2; mi++)                                 \
        _Pragma("unroll")                                            \
        for (int ni = 0; ni < 4; ni++)                               \
          acc[mi][ni] = __builtin_amdgcn_mfma_f32_16x16x32_bf16(     \
              af[mi], bfr[ni], acc[mi][ni], 0, 0, 0);                \
    }                                                                \
  } while (0)

  Set S0, S1;

  // ---- prologue: tiles 0,1 in flight; tile 0 staged to buf0 ----
  LOAD_SET(S0);          // tile 0
  LOAD_SET(S1);          // tile 1
  WRITE_SET(S0, sA[0], sB[0]);
  lds_barrier();

  // ---- main loop: 31 double half-steps (h = 0..61, all with loads) ----
  for (int j = 0; j < 31; ++j) {
    // even half h=2j: load tile 2j+2 -> S0; compute tile 2j (buf0);
    // write tile 2j+1 (S1, loaded one half ago) -> buf1
    LOAD_SET(S0);
    COMPUTE(sA[0], sB[0]);
    WRITE_SET(S1, sA[1], sB[1]);
    lds_barrier();
    // odd half h=2j+1: load tile 2j+3 -> S1; compute tile 2j+1 (buf1);
    // write tile 2j+2 (S0) -> buf0
    LOAD_SET(S1);
    COMPUTE(sA[1], sB[1]);
    WRITE_SET(S0, sA[0], sB[0]);
    lds_barrier();
  }

  // ---- tail: h=62 (compute 62, write 63), h=63 (compute 63) ----
  COMPUTE(sA[0], sB[0]);
  WRITE_SET(S1, sA[1], sB[1]);
  lds_barrier();
  COMPUTE(sA[1], sB[1]);

#undef LOAD_SET
#undef WRITE_SET
#undef COMPUTE

  // C/D layout: col = lane&15, row = (lane>>4)*4 + reg
  const int cr = (lane >> 4) * 4;
  const int cc = lane & 15;
#pragma unroll
  for (int mi = 0; mi < 2; mi++)
#pragma unroll
    for (int ni = 0; ni < 4; ni++) {
      float* cp = C + (size_t)(m0 + wm + mi * 16 + cr) * N_DIM +
                  (n0 + wn + ni * 16 + cc);
#pragma unroll
      for (int r = 0; r < 4; r++) cp[(size_t)r * N_DIM] = acc[mi][ni][r];
    }
}

extern "C" void kernel_launch(void* const* d_in, const int* in_sizes, int n_in,
                              void* d_out, int out_size, void* d_ws, size_t ws_size,
                              hipStream_t stream) {
  const float* x  = (const float*)d_in[0];   // (4,2048,1024,4) fp32
  const float* w  = (const float*)d_in[1];   // (1024,4) fp32
  const float* ws = (const float*)d_in[2];   // (1024,1024) fp32
  float* out = (float*)d_out;                // (4,2048,1024) fp32 = C[M][N]

  u16* w2 = (u16*)d_ws;                      // 4.2M u16 = 8 MB

  k_w2<<<4096, 256, 0, stream>>>(w, ws, w2);
  k_gemm<<<512, 512, 0, stream>>>(x, w2, out);
}

// Round 4
// 284.052 us; speedup vs baseline: 1.0315x; 1.0235x over previous
//
#include <hip/hip_runtime.h>

typedef unsigned short u16;
typedef u16 u16x4 __attribute__((ext_vector_type(4)));
typedef u16 u16x8 __attribute__((ext_vector_type(8)));
typedef float f32x4 __attribute__((ext_vector_type(4)));
typedef __bf16 bf16x8 __attribute__((ext_vector_type(8)));

#define M_DIM 8192   // B*H = 4*2048
#define N_DIM 1024   // O
#define K_DIM 4096   // I*(D+1) = 1024*4
#define BM 128
#define BN 256
#define BK 32

__device__ __forceinline__ u16 f2bf(float f) {
  unsigned u = __float_as_uint(f);
  u += 0x7FFFu + ((u >> 16) & 1u);   // round-to-nearest-even
  return (u16)(u >> 16);
}

// ---- kernel 1: W2[o][i*4+d] = ws[o][i] * w[o][d], bf16 [N][K] ----
__global__ __launch_bounds__(256) void k_w2(const float* __restrict__ w,
                                            const float* __restrict__ ws,
                                            u16* __restrict__ w2) {
  int idx = blockIdx.x * 256 + threadIdx.x;  // idx = o*1024 + i
  int o = idx >> 10;
  float s = ws[idx];
  f32x4 wv = *(const f32x4*)(w + o * 4);
  u16x4 r;
  r[0] = f2bf(s * wv[0]); r[1] = f2bf(s * wv[1]);
  r[2] = f2bf(s * wv[2]); r[3] = f2bf(s * wv[3]);
  *(u16x4*)(w2 + (size_t)idx * 4) = r;
}

// ---- kernel 2: fused cvt+GEMM. 128x256 block tile, BK=32, 8 waves of
// 64x64. Depth-2 counted register pipeline: iter it = issue loads(it+2)
// -> COMPUTE(it) -> cvt+ds_write(it+1) -> lgkmcnt(0)+s_barrier. vmcnt is
// never drained; the memory-clobber barrier asm makes load-sinking
// illegal, so ~2 tiles of loads stay in flight per wave at all times. ----

__device__ __forceinline__ void bar() {
  asm volatile("s_waitcnt lgkmcnt(0)" ::: "memory");
  __builtin_amdgcn_s_barrier();
}

__global__ __launch_bounds__(512, 2) void k_gemm(const float* __restrict__ A,
                                                 const u16* __restrict__ Bt,
                                                 float* __restrict__ C) {
  __shared__ u16 sA[2][BM * BK];   // bf16, swizzled; 2 x 8 KB
  __shared__ u16 sB[2][BN * BK];   // bf16, swizzled; 2 x 16 KB

  const int t    = threadIdx.x;
  const int lane = t & 63;
  const int wid  = t >> 6;           // 0..7

  // 256 blocks: XCD x owns m-panels x*8..x*8+7; the 4 n-blocks of each
  // m-panel are consecutive -> same XCD L2 (A panel fetched ~once).
  const int L   = blockIdx.x;
  const int xcd = L & 7;
  const int jb  = L >> 3;            // 0..31
  const int m0  = (xcd * 8 + (jb >> 2)) * BM;
  const int n0  = (jb & 3) * BN;

  // --- A staging: thread t -> row ra=t>>2, 16B-chunk qa=t&3 (8 floats).
  // LDS row = 32 bf16 = 64 B; swizzle slot = chunk ^ ((row>>1)&3).
  const int ra = t >> 2, qa = t & 3;
  const float* gA = A + (size_t)(m0 + ra) * K_DIM + qa * 8;
  const int wAoff = ra * 32 + (qa ^ ((ra >> 1) & 3)) * 8;   // u16 units

  // --- B staging: thread t -> row rb=t>>1, chunks 2u,2u+1 (u=t&1).
  const int rb = t >> 1, ub = t & 1;
  const u16* gB = Bt + (size_t)(n0 + rb) * K_DIM + ub * 16;
  const int mbs = (rb >> 1) & 3;
  const int wB0off = rb * 32 + ((2 * ub) ^ mbs) * 8;
  const int wB1off = rb * 32 + ((2 * ub + 1) ^ mbs) * 8;

  // wave tile 64x64: 2(M) x 4(N) wave grid; 4x4 MFMA 16x16x32 per K-step
  const int wm  = (wid >> 2) * 64;
  const int wn  = (wid & 3) * 64;
  const int fr  = lane & 15;
  const int lc  = lane >> 4;         // k-chunk 0..3
  const int fsl = (lc ^ ((fr >> 1) & 3)) * 8;  // swizzled frag slot (u16)

  f32x4 acc[4][4];
#pragma unroll
  for (int i = 0; i < 4; i++)
#pragma unroll
    for (int j = 0; j < 4; j++) acc[i][j] = (f32x4){0.f, 0.f, 0.f, 0.f};

  f32x4 a0_0, a0_1, a1_0, a1_1;   // A prefetch sets (fp32)
  u16x8 b0_0, b0_1, b1_0, b1_1;   // B prefetch sets (bf16 raw)

#define ISSUE(aX0, aX1, bX0, bX1)       \
  do {                                  \
    aX0 = *(const f32x4*)(gA);          \
    aX1 = *(const f32x4*)(gA + 4);      \
    bX0 = *(const u16x8*)(gB);          \
    bX1 = *(const u16x8*)(gB + 8);      \
    gA += BK; gB += BK;                 \
  } while (0)

#define WRITE(buf, aX0, aX1, bX0, bX1)               \
  do {                                               \
    bf16x8 av;                                       \
    av[0] = (__bf16)aX0[0]; av[1] = (__bf16)aX0[1];  \
    av[2] = (__bf16)aX0[2]; av[3] = (__bf16)aX0[3];  \
    av[4] = (__bf16)aX1[0]; av[5] = (__bf16)aX1[1];  \
    av[6] = (__bf16)aX1[2]; av[7] = (__bf16)aX1[3];  \
    *(bf16x8*)(sA[buf] + wAoff) = av;                \
    *(u16x8*)(sB[buf] + wB0off) = bX0;               \
    *(u16x8*)(sB[buf] + wB1off) = bX1;               \
  } while (0)

#define COMPUTE(buf)                                                     \
  do {                                                                   \
    bf16x8 af[4], bfv[4];                                                \
    _Pragma("unroll")                                                    \
    for (int mi = 0; mi < 4; mi++)                                       \
      af[mi] = *(const bf16x8*)(sA[buf] + (wm + mi * 16 + fr) * 32 + fsl); \
    _Pragma("unroll")                                                    \
    for (int ni = 0; ni < 4; ni++)                                       \
      bfv[ni] = *(const bf16x8*)(sB[buf] + (wn + ni * 16 + fr) * 32 + fsl); \
    _Pragma("unroll")                                                    \
    for (int mi = 0; mi < 4; mi++)                                       \
      _Pragma("unroll")                                                  \
      for (int ni = 0; ni < 4; ni++)                                     \
        acc[mi][ni] = __builtin_amdgcn_mfma_f32_16x16x32_bf16(           \
            af[mi], bfv[ni], acc[mi][ni], 0, 0, 0);                      \
  } while (0)

  // ---- prologue: tiles 0,1 issued; tile 0 staged to buf0 ----
  ISSUE(a0_0, a0_1, b0_0, b0_1);   // tile 0 -> set0
  ISSUE(a1_0, a1_1, b1_0, b1_1);   // tile 1 -> set1
  WRITE(0, a0_0, a0_1, b0_0, b0_1);
  bar();

  // ---- main loop: it = 0..125 (63 double iters), all with issues ----
  for (int jj = 0; jj < 63; ++jj) {
    ISSUE(a0_0, a0_1, b0_0, b0_1);        // tile 2jj+2 -> set0
    COMPUTE(0);                           // tile 2jj
    WRITE(1, a1_0, a1_1, b1_0, b1_1);     // tile 2jj+1 -> buf1
    bar();
    ISSUE(a1_0, a1_1, b1_0, b1_1);        // tile 2jj+3 -> set1
    COMPUTE(1);                           // tile 2jj+1
    WRITE(0, a0_0, a0_1, b0_0, b0_1);     // tile 2jj+2 -> buf0
    bar();
  }

  // ---- tail: it=126 (compute 126, write 127), it=127 (compute 127) ----
  COMPUTE(0);                             // tile 126
  WRITE(1, a1_0, a1_1, b1_0, b1_1);       // tile 127 -> buf1
  bar();
  COMPUTE(1);                             // tile 127

#undef ISSUE
#undef WRITE
#undef COMPUTE

  // C/D layout: col = lane&15, row = (lane>>4)*4 + reg
  const int cr = (lane >> 4) * 4;
  const int cc = lane & 15;
#pragma unroll
  for (int mi = 0; mi < 4; mi++)
#pragma unroll
    for (int ni = 0; ni < 4; ni++) {
      float* cp = C + (size_t)(m0 + wm + mi * 16 + cr) * N_DIM +
                  (n0 + wn + ni * 16 + cc);
#pragma unroll
      for (int r = 0; r < 4; r++) cp[(size_t)r * N_DIM] = acc[mi][ni][r];
    }
}

extern "C" void kernel_launch(void* const* d_in, const int* in_sizes, int n_in,
                              void* d_out, int out_size, void* d_ws, size_t ws_size,
                              hipStream_t stream) {
  const float* x  = (const float*)d_in[0];   // (4,2048,1024,4) fp32
  const float* w  = (const float*)d_in[1];   // (1024,4) fp32
  const float* ws = (const float*)d_in[2];   // (1024,1024) fp32
  float* out = (float*)d_out;                // (4,2048,1024) fp32 = C[M][N]

  u16* w2 = (u16*)d_ws;                      // 4.2M u16 = 8 MB

  k_w2<<<4096, 256, 0, stream>>>(w, ws, w2);
  k_gemm<<<256, 512, 0, stream>>>(x, w2, out);
}

// Round 7
// 281.691 us; speedup vs baseline: 1.0401x; 1.0084x over previous
//
#include <hip/hip_runtime.h>

typedef unsigned short u16;
typedef u16 u16x4 __attribute__((ext_vector_type(4)));
typedef float f32x4 __attribute__((ext_vector_type(4)));
typedef __bf16 bf16x8 __attribute__((ext_vector_type(8)));

#define M_DIM 8192   // B*H = 4*2048
#define N_DIM 1024   // O
#define K_DIM 4096   // I*(D+1) = 1024*4
#define BM 256
#define BN 128
#define BK 32

__device__ __forceinline__ u16 f2bf(float f) {
  unsigned u = __float_as_uint(f);
  u += 0x7FFFu + ((u >> 16) & 1u);   // round-to-nearest-even
  return (u16)(u >> 16);
}

// ---- kernel 1: x fp32 -> bf16 (lane-contiguous 16B read / 8B write) ----
__global__ __launch_bounds__(256) void k_cvt(const float* __restrict__ x,
                                             u16* __restrict__ y) {
  long i = ((long)blockIdx.x * 256 + threadIdx.x) * 4;
  f32x4 a = *(const f32x4*)(x + i);
  u16x4 r;
  r[0] = f2bf(a[0]); r[1] = f2bf(a[1]); r[2] = f2bf(a[2]); r[3] = f2bf(a[3]);
  *(u16x4*)(y + i) = r;
}

// ---- kernel 2: W2[o][i*4+d] = ws[o][i] * w[o][d], bf16 [N][K] ----
__global__ __launch_bounds__(256) void k_w2(const float* __restrict__ w,
                                            const float* __restrict__ ws,
                                            u16* __restrict__ w2) {
  int idx = blockIdx.x * 256 + threadIdx.x;  // idx = o*1024 + i
  int o = idx >> 10;
  float s = ws[idx];
  f32x4 wv = *(const f32x4*)(w + o * 4);
  u16x4 r;
  r[0] = f2bf(s * wv[0]); r[1] = f2bf(s * wv[1]);
  r[2] = f2bf(s * wv[2]); r[3] = f2bf(s * wv[3]);
  *(u16x4*)(w2 + (size_t)idx * 4) = r;
}

// ---- kernel 3: bf16 GEMM, counted-vmcnt phase schedule, 64 KiB LDS.
// BM=256 BN=128 BK=32, 8 waves (64x64 out each), 2 phases per K-tile.
// A triple-buffered (staged 2 tiles ahead), B double-buffered (1 ahead),
// via global_load_lds (linear LDS dest, pre-swizzled global source).
// ONE counted vmcnt(2) per K-tile; never drained inside the loop.
// 64 KiB LDS -> 2 blocks/CU. ----
typedef __attribute__((address_space(1))) const void gvoid_t;
typedef __attribute__((address_space(3))) void lvoid_t;
__device__ __forceinline__ void gll16(const void* g, void* l) {
  __builtin_amdgcn_global_load_lds((gvoid_t*)g, (lvoid_t*)l, 16, 0, 0);
}

__global__ __launch_bounds__(512, 4) void k_gemm(const u16* __restrict__ A,
                                                 const u16* __restrict__ Bt,
                                                 float* __restrict__ C) {
  __shared__ u16 lds[32768];           // 64 KiB total
  u16* const sA0 = lds;                // 3 x 16 KB (A: 256 x 32 bf16)
  u16* const sA1 = lds + 8192;
  u16* const sA2 = lds + 16384;
  u16* const sB0 = lds + 24576;        // 2 x 8 KB (B: 128 x 32 bf16)
  u16* const sB1 = lds + 28672;

  const int t    = threadIdx.x;
  const int lane = t & 63;
  const int wid  = t >> 6;           // 0..7

  // XCD swizzle: 256 blocks; xcd = L&7 owns m-panels 4x..4x+3, each with
  // its 8 n-blocks consecutive -> one XCD L2 (A panel fetched once).
  const int L   = blockIdx.x;
  const int xcd = L & 7;
  const int jb  = L >> 3;            // 0..31
  const int m0  = (xcd * 4 + (jb >> 3)) * BM;
  const int n0  = (jb & 7) * BN;

  // --- staging geometry: rows are 32 bf16 = 64 B = 4 x 16B chunks.
  // LDS slot s (16B) holds row r=s>>2, logical chunk cg=(s&3)^(r&3).
  // gll16 dest is linear in s (base + lane*16); swizzle lives in the
  // pre-swizzled global source address. ---
  const u16* gA0; const u16* gA1; int dA0, dA1;
  {
    int s = t,       r = s >> 2, cg = (s & 3) ^ (r & 3);
    gA0 = A + (size_t)(m0 + r) * K_DIM + cg * 8;  dA0 = s * 8;
    s = 512 + t;     r = s >> 2; cg = (s & 3) ^ (r & 3);
    gA1 = A + (size_t)(m0 + r) * K_DIM + cg * 8;  dA1 = s * 8;
  }
  const u16* gB; int dBo;
  {
    int s = t, r = s >> 2, cg = (s & 3) ^ (r & 3);
    gB = Bt + (size_t)(n0 + r) * K_DIM + cg * 8;  dBo = s * 8;
  }

  // wave tile 64x64: wave grid 4(M) x 2(N); 4x4 MFMA frags per K-tile
  const int wm = (wid >> 1) * 64;
  const int wn = (wid & 1) * 64;
  const int fr = lane & 15;
  const int lc = lane >> 4;          // 16B chunk within the 32-wide K-tile

  f32x4 acc[4][4];
#pragma unroll
  for (int i = 0; i < 4; i++)
#pragma unroll
    for (int j = 0; j < 4; j++) acc[i][j] = (f32x4){0.f, 0.f, 0.f, 0.f};

  // ---- prologue: A(0)x2, B(0)x1, A(1)x2; leave A(1) in flight ----
  gll16(gA0, sA0 + dA0); gll16(gA1, sA0 + dA1);
  gll16(gB,  sB0 + dBo);
  gll16(gA0 + 32, sA1 + dA0); gll16(gA1 + 32, sA1 + dA1);
  asm volatile("s_waitcnt vmcnt(2)" ::: "memory");
  __builtin_amdgcn_s_barrier();

  u16 *pAc = sA0, *pAn = sA1, *pAs = sA2;
  u16 *pBc = sB0, *pBs = sB1;

#define AREAD(dst, MI)                                                     \
  do {                                                                     \
    int r_ = wm + (MI) * 16 + fr;                                          \
    dst = *(const bf16x8*)(pAc + r_ * 32 + ((lc ^ (r_ & 3)) * 8));         \
  } while (0)

  // ---- main loop: 128 K-tiles x 2 phases; staging wraps (junk lands in
  // buffers never read again — in-bounds, harmless) ----
  for (int tt = 0; tt < 128; ++tt) {
    const int ka = ((tt + 2) & 127) * BK;   // A staged 2 tiles ahead
    const int kb = ((tt + 1) & 127) * BK;   // B staged 1 tile ahead
    bf16x8 af0, af1, bq[4];

    // ---- ph0: A frags mi0-1 + all B frags; stage B(t+1) ----
    AREAD(af0, 0); AREAD(af1, 1);
#pragma unroll
    for (int n_ = 0; n_ < 4; n_++) {
      int r_ = wn + n_ * 16 + fr;
      bq[n_] = *(const bf16x8*)(pBc + r_ * 32 + ((lc ^ (r_ & 3)) * 8));
    }
    gll16(gB + kb, pBs + dBo);
    __builtin_amdgcn_s_barrier();
    asm volatile("s_waitcnt lgkmcnt(0)" ::: "memory");
    __builtin_amdgcn_s_setprio(1);
#pragma unroll
    for (int n_ = 0; n_ < 4; n_++) {
      acc[0][n_] = __builtin_amdgcn_mfma_f32_16x16x32_bf16(af0, bq[n_],
                                                           acc[0][n_], 0, 0, 0);
      acc[1][n_] = __builtin_amdgcn_mfma_f32_16x16x32_bf16(af1, bq[n_],
                                                           acc[1][n_], 0, 0, 0);
    }
    __builtin_amdgcn_s_setprio(0);
    __builtin_amdgcn_s_barrier();

    // ---- ph1: A frags mi2-3; stage A(t+2); counted vmcnt ----
    AREAD(af0, 2); AREAD(af1, 3);
    gll16(gA0 + ka, pAs + dA0); gll16(gA1 + ka, pAs + dA1);
    // queue (oldest first): A(t+1)x2, B(t+1)x1, A(t+2)x2 -> retire 3,
    // keep A(t+2) in flight: tile t+1 is ready, lookahead preserved.
    asm volatile("s_waitcnt vmcnt(2)" ::: "memory");
    __builtin_amdgcn_s_barrier();
    asm volatile("s_waitcnt lgkmcnt(0)" ::: "memory");
    __builtin_amdgcn_s_setprio(1);
#pragma unroll
    for (int n_ = 0; n_ < 4; n_++) {
      acc[2][n_] = __builtin_amdgcn_mfma_f32_16x16x32_bf16(af0, bq[n_],
                                                           acc[2][n_], 0, 0, 0);
      acc[3][n_] = __builtin_amdgcn_mfma_f32_16x16x32_bf16(af1, bq[n_],
                                                           acc[3][n_], 0, 0, 0);
    }
    __builtin_amdgcn_s_setprio(0);
    __builtin_amdgcn_s_barrier();

    // rotate buffers: A period-3, B period-2
    u16* tmp = pAc; pAc = pAn; pAn = pAs; pAs = tmp;
    tmp = pBc; pBc = pBs; pBs = tmp;
  }

#undef AREAD

  // C/D layout: col = lane&15, row = (lane>>4)*4 + reg
  const int cr = (lane >> 4) * 4;
  const int cc = lane & 15;
#pragma unroll
  for (int mi = 0; mi < 4; mi++)
#pragma unroll
    for (int ni = 0; ni < 4; ni++) {
      float* cp = C + (size_t)(m0 + wm + mi * 16 + cr) * N_DIM +
                  (n0 + wn + ni * 16 + cc);
#pragma unroll
      for (int r = 0; r < 4; r++) cp[(size_t)r * N_DIM] = acc[mi][ni][r];
    }
}

extern "C" void kernel_launch(void* const* d_in, const int* in_sizes, int n_in,
                              void* d_out, int out_size, void* d_ws, size_t ws_size,
                              hipStream_t stream) {
  const float* x  = (const float*)d_in[0];   // (4,2048,1024,4) fp32
  const float* w  = (const float*)d_in[1];   // (1024,4) fp32
  const float* ws = (const float*)d_in[2];   // (1024,1024) fp32
  float* out = (float*)d_out;                // (4,2048,1024) fp32 = C[M][N]

  u16* xbf = (u16*)d_ws;                         // 33.5M u16 = 64 MB
  u16* w2  = xbf + (size_t)M_DIM * K_DIM;        // 4.2M u16 = 8 MB

  k_cvt<<<32768, 256, 0, stream>>>(x, xbf);
  k_w2<<<4096, 256, 0, stream>>>(w, ws, w2);
  k_gemm<<<256, 512, 0, stream>>>(xbf, w2, out);
}